// Round 2
// baseline (4063.714 us; speedup 1.0000x reference)
//
#include <hip/hip_runtime.h>
#include <math.h>

#define B 2
#define S 2048
#define D 2048
#define H 32
#define HD 64
#define M (B*S)

// ---------------------------------------------------------------------------
// GEMM: C[M,N] = A[M,K] * Bm[N,K]^T   (torch Linear: y = x @ W.T)
// 64x64 tile, BK=16, 256 threads, 4x4 acc/thread, k-major LDS for b128 reads.
// ---------------------------------------------------------------------------
#define TM 64
#define TN 64
#define TK 16

__global__ __launch_bounds__(256) void gemm_abt(
    const float* __restrict__ A, const float* __restrict__ Bm,
    float* __restrict__ Cm, int Mdim, int Ndim, int Kdim)
{
    __shared__ float As[TK][TM + 4];   // +4 keeps float4 alignment, breaks conflicts
    __shared__ float Bs[TK][TN + 4];
    const int tid = threadIdx.x;
    const int tx = tid & 15, ty = tid >> 4;
    const int m0 = blockIdx.y * TM, n0 = blockIdx.x * TN;
    const int lr = tid >> 2;           // 0..63 tile row
    const int lc = (tid & 3) << 2;     // 0,4,8,12 k-offset
    float acc[4][4] = {};
    const float* Arow = A + (size_t)(m0 + lr) * Kdim + lc;
    const float* Brow = Bm + (size_t)(n0 + lr) * Kdim + lc;
    for (int k0 = 0; k0 < Kdim; k0 += TK) {
        float4 av = *(const float4*)(Arow + k0);
        float4 bv = *(const float4*)(Brow + k0);
        As[lc+0][lr]=av.x; As[lc+1][lr]=av.y; As[lc+2][lr]=av.z; As[lc+3][lr]=av.w;
        Bs[lc+0][lr]=bv.x; Bs[lc+1][lr]=bv.y; Bs[lc+2][lr]=bv.z; Bs[lc+3][lr]=bv.w;
        __syncthreads();
        #pragma unroll
        for (int kk = 0; kk < TK; ++kk) {
            float4 a4 = *(const float4*)&As[kk][ty*4];
            float4 b4 = *(const float4*)&Bs[kk][tx*4];
            float a[4] = {a4.x, a4.y, a4.z, a4.w};
            float b[4] = {b4.x, b4.y, b4.z, b4.w};
            #pragma unroll
            for (int i2 = 0; i2 < 4; ++i2)
                #pragma unroll
                for (int j2 = 0; j2 < 4; ++j2)
                    acc[i2][j2] += a[i2] * b[j2];
        }
        __syncthreads();
    }
    #pragma unroll
    for (int i2 = 0; i2 < 4; ++i2) {
        float4 c4 = make_float4(acc[i2][0], acc[i2][1], acc[i2][2], acc[i2][3]);
        *(float4*)&Cm[(size_t)(m0 + ty*4 + i2) * Ndim + n0 + tx*4] = c4;
    }
}

// ---------------------------------------------------------------------------
// Forget gates: F[b,s,h] = logsigmoid(x[b,s,:] . Wf[h,:] + bf[h])
// One block per (b,s) row; x row staged in LDS; each wave handles 8 heads.
// ---------------------------------------------------------------------------
__global__ __launch_bounds__(256) void fgate_kernel(
    const float* __restrict__ x, const float* __restrict__ Wf,
    const float* __restrict__ bfv, float* __restrict__ F)
{
    __shared__ float xs[D];
    const int bs = blockIdx.x;
    const float* xr = x + (size_t)bs * D;
    for (int i = threadIdx.x * 4; i < D; i += 256 * 4)
        *(float4*)&xs[i] = *(const float4*)&xr[i];
    __syncthreads();
    const int wave = threadIdx.x >> 6, lane = threadIdx.x & 63;
    for (int h = wave * 8; h < wave * 8 + 8; ++h) {
        const float* wr = Wf + (size_t)h * D;
        float sum = 0.f;
        for (int i = lane * 4; i < D; i += 64 * 4) {
            float4 w4 = *(const float4*)&wr[i];
            sum += xs[i]*w4.x + xs[i+1]*w4.y + xs[i+2]*w4.z + xs[i+3]*w4.w;
        }
        #pragma unroll
        for (int off = 32; off > 0; off >>= 1) sum += __shfl_down(sum, off);
        if (lane == 0) {
            float z = sum + bfv[h];
            // stable log-sigmoid
            F[(size_t)bs * H + h] = fminf(z, 0.f) - log1pf(expf(-fabsf(z)));
        }
    }
}

// ---------------------------------------------------------------------------
// In-place inclusive cumsum of F over the S axis, per (b,h).
// One block per (b,h): 256 threads x 8 elems, block scan over partials.
// ---------------------------------------------------------------------------
__global__ __launch_bounds__(256) void cumsum_kernel(float* __restrict__ F)
{
    const int b = blockIdx.x >> 5;   // / H
    const int h = blockIdx.x & 31;   // % H
    float* base = F + (size_t)b * S * H + h;
    __shared__ float part[256];
    const int t = threadIdx.x;
    float v[8];
    float run = 0.f;
    #pragma unroll
    for (int i = 0; i < 8; ++i) {
        v[i] = base[(size_t)(t * 8 + i) * H];
        run += v[i];
        v[i] = run;
    }
    part[t] = run;
    __syncthreads();
    for (int off = 1; off < 256; off <<= 1) {
        float add = (t >= off) ? part[t - off] : 0.f;
        __syncthreads();
        part[t] += add;
        __syncthreads();
    }
    const float offs = (t > 0) ? part[t - 1] : 0.f;
    #pragma unroll
    for (int i = 0; i < 8; ++i)
        base[(size_t)(t * 8 + i) * H] = v[i] + offs;
}

// ---------------------------------------------------------------------------
// Causal attention with forget bias, flash-style online softmax.
// Block = (b, h, 256 q-rows); each thread owns one q row (q,o in registers).
// K/V tiles of 32 rows staged in LDS; inner loops read LDS via float4
// (wave-uniform addresses -> conflict-free broadcast b128 reads).
// score = (q.k)/sqrt(HD) + c_i - c_j
// ---------------------------------------------------------------------------
#define QROWS 256
#define KT 32
#define SCALE 0.125f  // 1/sqrt(64)

__global__ __launch_bounds__(256) void attn_kernel(
    const float* __restrict__ Q, const float* __restrict__ Km,
    const float* __restrict__ V, const float* __restrict__ C,
    float* __restrict__ O)
{
    const int qt = blockIdx.x, h = blockIdx.y, b = blockIdx.z;
    const int i = qt * QROWS + threadIdx.x;   // this thread's q row
    const size_t qoff = (size_t)(b * S + i) * D + h * HD;
    float q[HD], o[HD];
    #pragma unroll
    for (int d = 0; d < HD; d += 4) {
        float4 t4 = *(const float4*)(Q + qoff + d);
        q[d] = t4.x; q[d+1] = t4.y; q[d+2] = t4.z; q[d+3] = t4.w;
        o[d] = 0.f; o[d+1] = 0.f; o[d+2] = 0.f; o[d+3] = 0.f;
    }
    const float ci = C[(size_t)(b * S + i) * H + h];
    float mrun = -INFINITY, l = 0.f;
    __shared__ float Ks[KT][HD], Vs[KT][HD], cj[KT];
    const int ntiles = (qt + 1) * (QROWS / KT);
    for (int jt = 0; jt < ntiles; ++jt) {
        const int j0 = jt * KT;
        {
            const int r = threadIdx.x >> 3;          // 0..31
            const int c = (threadIdx.x & 7) << 3;    // 0..56
            const size_t goff = (size_t)(b * S + j0 + r) * D + h * HD + c;
            *(float4*)&Ks[r][c]     = *(const float4*)(Km + goff);
            *(float4*)&Ks[r][c + 4] = *(const float4*)(Km + goff + 4);
            *(float4*)&Vs[r][c]     = *(const float4*)(V + goff);
            *(float4*)&Vs[r][c + 4] = *(const float4*)(V + goff + 4);
            if (threadIdx.x < KT)
                cj[threadIdx.x] = C[(size_t)(b * S + j0 + threadIdx.x) * H + h];
        }
        __syncthreads();
        if (j0 <= i) {
            for (int jc = 0; jc < KT; jc += 8) {
                float sc[8], cmax = -INFINITY;
                #pragma unroll
                for (int jj = 0; jj < 8; ++jj) {
                    const int j = jc + jj;
                    const float4* kr = (const float4*)&Ks[j][0];
                    float s = 0.f;
                    #pragma unroll
                    for (int d4 = 0; d4 < HD / 4; ++d4) {
                        float4 k4 = kr[d4];
                        s += q[d4*4+0]*k4.x + q[d4*4+1]*k4.y
                           + q[d4*4+2]*k4.z + q[d4*4+3]*k4.w;
                    }
                    s = s * SCALE + (ci - cj[j]);
                    s = (j0 + j <= i) ? s : -INFINITY;
                    sc[jj] = s;
                    cmax = fmaxf(cmax, s);
                }
                if (cmax > -INFINITY) {   // skip fully-masked chunks (avoids inf-inf)
                    const float newm = fmaxf(mrun, cmax);
                    const float corr = expf(mrun - newm);  // 0 when mrun=-inf
                    l *= corr;
                    #pragma unroll
                    for (int d = 0; d < HD; ++d) o[d] *= corr;
                    #pragma unroll
                    for (int jj = 0; jj < 8; ++jj) {
                        const float p = expf(sc[jj] - newm);
                        l += p;
                        const float4* vr = (const float4*)&Vs[jc + jj][0];
                        #pragma unroll
                        for (int d4 = 0; d4 < HD / 4; ++d4) {
                            float4 v4 = vr[d4];
                            o[d4*4+0] += p * v4.x;
                            o[d4*4+1] += p * v4.y;
                            o[d4*4+2] += p * v4.z;
                            o[d4*4+3] += p * v4.w;
                        }
                    }
                    mrun = newm;
                }
            }
        }
        __syncthreads();
    }
    const float inv = 1.f / l;
    #pragma unroll
    for (int d = 0; d < HD; d += 4) {
        float4 t4 = make_float4(o[d]*inv, o[d+1]*inv, o[d+2]*inv, o[d+3]*inv);
        *(float4*)(O + qoff + d) = t4;
    }
}

// ---------------------------------------------------------------------------
extern "C" void kernel_launch(void* const* d_in, const int* in_sizes, int n_in,
                              void* d_out, int out_size, void* d_ws, size_t ws_size,
                              hipStream_t stream) {
    const float* x  = (const float*)d_in[0];
    const float* Wq = (const float*)d_in[1];
    const float* Wk = (const float*)d_in[2];
    const float* Wv = (const float*)d_in[3];
    const float* Wf = (const float*)d_in[4];
    const float* bf = (const float*)d_in[5];
    const float* Wo = (const float*)d_in[6];
    float* out = (float*)d_out;

    // workspace layout (floats): Q | K | V | F(cumsum gates) | O  ~= 135 MB
    float* Q  = (float*)d_ws;
    float* K  = Q + (size_t)M * D;
    float* V  = K + (size_t)M * D;
    float* Fc = V + (size_t)M * D;
    float* O  = Fc + (size_t)B * S * H;

    dim3 gblk(256);
    dim3 ggrid(D / TN, M / TM);
    gemm_abt<<<ggrid, gblk, 0, stream>>>(x, Wq, Q, M, D, D);
    gemm_abt<<<ggrid, gblk, 0, stream>>>(x, Wk, K, M, D, D);
    gemm_abt<<<ggrid, gblk, 0, stream>>>(x, Wv, V, M, D, D);
    fgate_kernel<<<dim3(M), dim3(256), 0, stream>>>(x, Wf, bf, Fc);
    cumsum_kernel<<<dim3(B * H), dim3(256), 0, stream>>>(Fc);
    attn_kernel<<<dim3(S / QROWS, H, B), dim3(256), 0, stream>>>(Q, K, V, Fc, O);
    gemm_abt<<<ggrid, gblk, 0, stream>>>(O, Wo, out, M, D, D);
}

// Round 3
// 2474.511 us; speedup vs baseline: 1.6422x; 1.6422x over previous
//
#include <hip/hip_runtime.h>
#include <math.h>

#define B 2
#define S 2048
#define D 2048
#define H 32
#define HD 64
#define M (B*S)

typedef short s16x8 __attribute__((ext_vector_type(8)));
typedef float f32x4 __attribute__((ext_vector_type(4)));

// fp32 -> bf16 (RNE) and back, pure bit ops
__device__ __forceinline__ unsigned short f2bf(float f) {
    unsigned u = __float_as_uint(f);
    return (unsigned short)((u + 0x7fffu + ((u >> 16) & 1u)) >> 16);
}
__device__ __forceinline__ float bf2f(unsigned short h) {
    return __uint_as_float(((unsigned)h) << 16);
}

// ---------------------------------------------------------------------------
// bf16x3 MFMA GEMM: C[M,N] = A[M,K] * Bw[N,K]^T, fp32 in/out.
// Each fp32 split hi+lo bf16; C = Ah*Bh + Ah*Bl + Al*Bh (near-fp32 accuracy).
// 128x128 tile, BK=32, 4 waves (each 64x64 quadrant, 4x4 16x16x32 frags).
// ---------------------------------------------------------------------------
#define GBM 128
#define GBN 128
#define GBK 32
#define GLD (GBK + 8)   // bf16 row stride 40 (=80B, banks spread, 16B aligned)

__global__ __launch_bounds__(256) void gemm_bf16x3(
    const float* __restrict__ A, const float* __restrict__ Bw,
    float* __restrict__ Cm, int Ndim, int Kdim)
{
    __shared__ unsigned short Ah[GBM * GLD], Al[GBM * GLD];
    __shared__ unsigned short Bh[GBN * GLD], Bl[GBN * GLD];
    const int tid = threadIdx.x;
    // XCD-aware swizzle (grid % 8 == 0 for all our shapes)
    const int nwg = gridDim.x, cpx = nwg >> 3;
    const int wg = (blockIdx.x & 7) * cpx + (blockIdx.x >> 3);
    const int ntn = Ndim / GBN;
    const int m0 = (wg / ntn) * GBM, n0 = (wg % ntn) * GBN;

    const int row = tid >> 1;            // 0..127
    const int seg = (tid & 1) << 4;      // 0 or 16 floats
    const float* Arow = A + (size_t)(m0 + row) * Kdim + seg;
    const float* Brow = Bw + (size_t)(n0 + row) * Kdim + seg;
    const int sbase = row * GLD + seg;

    const int wv = tid >> 6, lane = tid & 63;
    const int wr = (wv >> 1) << 6, wc = (wv & 1) << 6;
    const int fr = lane & 15, ko = (lane >> 4) << 3;

    f32x4 acc[4][4] = {};
    for (int k0 = 0; k0 < Kdim; k0 += GBK) {
        // ---- stage A,B tiles: fp32 -> hi/lo bf16 in LDS
        {
            float fa[16], fb[16];
            #pragma unroll
            for (int j4 = 0; j4 < 4; ++j4) {
                *(float4*)&fa[j4 * 4] = *(const float4*)(Arow + k0 + j4 * 4);
                *(float4*)&fb[j4 * 4] = *(const float4*)(Brow + k0 + j4 * 4);
            }
            unsigned short hv[16], lv[16], hw[16], lw[16];
            #pragma unroll
            for (int j = 0; j < 16; ++j) {
                unsigned short h = f2bf(fa[j]);
                hv[j] = h; lv[j] = f2bf(fa[j] - bf2f(h));
                unsigned short g = f2bf(fb[j]);
                hw[j] = g; lw[j] = f2bf(fb[j] - bf2f(g));
            }
            *(s16x8*)&Ah[sbase]     = *(s16x8*)&hv[0];
            *(s16x8*)&Ah[sbase + 8] = *(s16x8*)&hv[8];
            *(s16x8*)&Al[sbase]     = *(s16x8*)&lv[0];
            *(s16x8*)&Al[sbase + 8] = *(s16x8*)&lv[8];
            *(s16x8*)&Bh[sbase]     = *(s16x8*)&hw[0];
            *(s16x8*)&Bh[sbase + 8] = *(s16x8*)&hw[8];
            *(s16x8*)&Bl[sbase]     = *(s16x8*)&lw[0];
            *(s16x8*)&Bl[sbase + 8] = *(s16x8*)&lw[8];
        }
        __syncthreads();
        // ---- fragments + MFMA
        s16x8 fah[4], fal[4], fbh[4], fbl[4];
        #pragma unroll
        for (int m = 0; m < 4; ++m) {
            const int r = (wr + m * 16 + fr) * GLD + ko;
            fah[m] = *(s16x8*)&Ah[r];
            fal[m] = *(s16x8*)&Al[r];
        }
        #pragma unroll
        for (int n = 0; n < 4; ++n) {
            const int r = (wc + n * 16 + fr) * GLD + ko;
            fbh[n] = *(s16x8*)&Bh[r];
            fbl[n] = *(s16x8*)&Bl[r];
        }
        #pragma unroll
        for (int m = 0; m < 4; ++m)
            #pragma unroll
            for (int n = 0; n < 4; ++n) {
                acc[m][n] = __builtin_amdgcn_mfma_f32_16x16x32_bf16(fah[m], fbh[n], acc[m][n], 0, 0, 0);
                acc[m][n] = __builtin_amdgcn_mfma_f32_16x16x32_bf16(fah[m], fbl[n], acc[m][n], 0, 0, 0);
                acc[m][n] = __builtin_amdgcn_mfma_f32_16x16x32_bf16(fal[m], fbh[n], acc[m][n], 0, 0, 0);
            }
        __syncthreads();
    }
    // ---- C write: col = lane&15 (B side), row = (lane>>4)*4 + reg (A side)
    const int crow0 = m0 + wr + ((lane >> 4) << 2);
    const int ccol0 = n0 + wc + fr;
    #pragma unroll
    for (int m = 0; m < 4; ++m)
        #pragma unroll
        for (int n = 0; n < 4; ++n)
            #pragma unroll
            for (int r = 0; r < 4; ++r)
                Cm[(size_t)(crow0 + m * 16 + r) * Ndim + ccol0 + n * 16] = acc[m][n][r];
}

// ---------------------------------------------------------------------------
// Forget gates: F[b,s,h] = logsigmoid(x[b,s,:] . Wf[h,:] + bf[h])
// ---------------------------------------------------------------------------
__global__ __launch_bounds__(256) void fgate_kernel(
    const float* __restrict__ x, const float* __restrict__ Wf,
    const float* __restrict__ bfv, float* __restrict__ F)
{
    __shared__ float xs[D];
    const int bs = blockIdx.x;
    const float* xr = x + (size_t)bs * D;
    for (int i = threadIdx.x * 4; i < D; i += 256 * 4)
        *(float4*)&xs[i] = *(const float4*)&xr[i];
    __syncthreads();
    const int wave = threadIdx.x >> 6, lane = threadIdx.x & 63;
    for (int h = wave * 8; h < wave * 8 + 8; ++h) {
        const float* wr = Wf + (size_t)h * D;
        float sum = 0.f;
        for (int i = lane * 4; i < D; i += 64 * 4) {
            float4 w4 = *(const float4*)&wr[i];
            sum += xs[i]*w4.x + xs[i+1]*w4.y + xs[i+2]*w4.z + xs[i+3]*w4.w;
        }
        #pragma unroll
        for (int off = 32; off > 0; off >>= 1) sum += __shfl_down(sum, off);
        if (lane == 0) {
            float z = sum + bfv[h];
            F[(size_t)bs * H + h] = fminf(z, 0.f) - log1pf(expf(-fabsf(z)));
        }
    }
}

// ---------------------------------------------------------------------------
// In-place inclusive cumsum of F over S, per (b,h).
// ---------------------------------------------------------------------------
__global__ __launch_bounds__(256) void cumsum_kernel(float* __restrict__ F)
{
    const int b = blockIdx.x >> 5;
    const int h = blockIdx.x & 31;
    float* base = F + (size_t)b * S * H + h;
    __shared__ float part[256];
    const int t = threadIdx.x;
    float v[8];
    float run = 0.f;
    #pragma unroll
    for (int i = 0; i < 8; ++i) {
        v[i] = base[(size_t)(t * 8 + i) * H];
        run += v[i];
        v[i] = run;
    }
    part[t] = run;
    __syncthreads();
    for (int off = 1; off < 256; off <<= 1) {
        float add = (t >= off) ? part[t - off] : 0.f;
        __syncthreads();
        part[t] += add;
        __syncthreads();
    }
    const float offs = (t > 0) ? part[t - 1] : 0.f;
    #pragma unroll
    for (int i = 0; i < 8; ++i)
        base[(size_t)(t * 8 + i) * H] = v[i] + offs;
}

// ---------------------------------------------------------------------------
// Causal attention with forget bias, flash online softmax, split-j partials.
// Grid: (S/QROWS, splits, B*H); qt reversed for LPT (big tiles first).
// Writes UNNORMALIZED o + (m, l); attn_merge combines splits + normalizes.
// defer-max (T13): skip o-rescale unless chunk max exceeds mrun + 8.
// ---------------------------------------------------------------------------
#define QROWS 256
#define KT 32
#define SCALE 0.125f  // 1/sqrt(64)
#define DEFER 8.0f

__global__ __launch_bounds__(256) void attn_kernel(
    const float* __restrict__ Q, const float* __restrict__ Km,
    const float* __restrict__ V, const float* __restrict__ C,
    float* __restrict__ Op, float* __restrict__ ML, int splits)
{
    const int qt = (int)gridDim.x - 1 - blockIdx.x;   // LPT ordering
    const int sp = blockIdx.y;
    const int b = blockIdx.z >> 5, h = blockIdx.z & 31;
    const int i = qt * QROWS + threadIdx.x;
    const size_t qoff = (size_t)(b * S + i) * D + h * HD;
    const size_t R = (size_t)M * H;

    float q[HD], o[HD];
    #pragma unroll
    for (int d = 0; d < HD; d += 4) {
        float4 t4 = *(const float4*)(Q + qoff + d);
        q[d] = t4.x; q[d+1] = t4.y; q[d+2] = t4.z; q[d+3] = t4.w;
        o[d] = 0.f; o[d+1] = 0.f; o[d+2] = 0.f; o[d+3] = 0.f;
    }
    const float ci = C[(size_t)(b * S + i) * H + h];
    float mrun = -INFINITY, l = 0.f;
    __shared__ float Ks[KT][HD], Vs[KT][HD], cj[KT];

    const int ntiles = (qt + 1) * (QROWS / KT);
    int t0 = 0, t1 = ntiles;
    if (splits == 2) { const int half = ntiles >> 1; t0 = sp ? half : 0; t1 = sp ? ntiles : half; }

    for (int jt = t0; jt < t1; ++jt) {
        const int j0 = jt * KT;
        {
            const int r = threadIdx.x >> 3;
            const int c = (threadIdx.x & 7) << 3;
            const size_t goff = (size_t)(b * S + j0 + r) * D + h * HD + c;
            *(float4*)&Ks[r][c]     = *(const float4*)(Km + goff);
            *(float4*)&Ks[r][c + 4] = *(const float4*)(Km + goff + 4);
            *(float4*)&Vs[r][c]     = *(const float4*)(V + goff);
            *(float4*)&Vs[r][c + 4] = *(const float4*)(V + goff + 4);
            if (threadIdx.x < KT)
                cj[threadIdx.x] = C[(size_t)(b * S + j0 + threadIdx.x) * H + h];
        }
        __syncthreads();
        if (j0 <= i) {
            for (int jc = 0; jc < KT; jc += 8) {
                float sc[8], cmax = -INFINITY;
                #pragma unroll
                for (int jj = 0; jj < 8; ++jj) {
                    const int j = jc + jj;
                    const float4* kr = (const float4*)&Ks[j][0];
                    float s = 0.f;
                    #pragma unroll
                    for (int d4 = 0; d4 < HD / 4; ++d4) {
                        float4 k4 = kr[d4];
                        s += q[d4*4+0]*k4.x + q[d4*4+1]*k4.y
                           + q[d4*4+2]*k4.z + q[d4*4+3]*k4.w;
                    }
                    s = s * SCALE + (ci - cj[j]);
                    s = (j0 + j <= i) ? s : -INFINITY;
                    sc[jj] = s;
                    cmax = fmaxf(cmax, s);
                }
                if (cmax > -INFINITY) {
                    if (cmax > mrun + DEFER) {          // rescale only when needed
                        const float corr = __expf(mrun - cmax);  // 0 when mrun=-inf
                        l *= corr;
                        #pragma unroll
                        for (int d = 0; d < HD; ++d) o[d] *= corr;
                        mrun = cmax;
                    }
                    #pragma unroll
                    for (int jj = 0; jj < 8; ++jj) {
                        const float p = __expf(sc[jj] - mrun);   // bounded by e^DEFER
                        l += p;
                        const float4* vr = (const float4*)&Vs[jc + jj][0];
                        #pragma unroll
                        for (int d4 = 0; d4 < HD / 4; ++d4) {
                            float4 v4 = vr[d4];
                            o[d4*4+0] += p * v4.x;
                            o[d4*4+1] += p * v4.y;
                            o[d4*4+2] += p * v4.z;
                            o[d4*4+3] += p * v4.w;
                        }
                    }
                }
            }
        }
        __syncthreads();
    }
    // write unnormalized partials
    const size_t r = (size_t)(b * S + i) * H + h;
    float* op = Op + (size_t)sp * R * HD + r * HD;
    #pragma unroll
    for (int d = 0; d < HD; d += 4)
        *(float4*)(op + d) = make_float4(o[d], o[d+1], o[d+2], o[d+3]);
    float* ml = ML + (size_t)sp * R * 2 + r * 2;
    ml[0] = mrun; ml[1] = l;
}

// Merge split partials; writes normalized result in place into Op[0].
__global__ __launch_bounds__(256) void attn_merge(
    float* __restrict__ Op, const float* __restrict__ ML, int splits)
{
    const size_t R = (size_t)M * H;
    const size_t r = (size_t)blockIdx.x * 4 + (threadIdx.x >> 6);
    const int d = threadIdx.x & 63;
    float m = -INFINITY;
    for (int s = 0; s < splits; ++s) m = fmaxf(m, ML[(size_t)s * R * 2 + r * 2]);
    float lsum = 0.f, osum = 0.f;
    for (int s = 0; s < splits; ++s) {
        const float ms = ML[(size_t)s * R * 2 + r * 2];
        const float ls = ML[(size_t)s * R * 2 + r * 2 + 1];
        const float w = __expf(ms - m);   // 0 when ms = -inf
        lsum += w * ls;
        osum += w * Op[(size_t)s * R * HD + r * HD + d];
    }
    Op[r * HD + d] = osum / lsum;
}

// ---------------------------------------------------------------------------
extern "C" void kernel_launch(void* const* d_in, const int* in_sizes, int n_in,
                              void* d_out, int out_size, void* d_ws, size_t ws_size,
                              hipStream_t stream) {
    const float* x  = (const float*)d_in[0];
    const float* Wq = (const float*)d_in[1];
    const float* Wk = (const float*)d_in[2];
    const float* Wv = (const float*)d_in[3];
    const float* Wf = (const float*)d_in[4];
    const float* bf = (const float*)d_in[5];
    const float* Wo = (const float*)d_in[6];
    float* out = (float*)d_out;

    const size_t R = (size_t)M * H;
    // ws layout (floats): Q | K | V | Fc | ML[splits] | Op[splits]
    float* Q  = (float*)d_ws;
    float* K  = Q + (size_t)M * D;
    float* V  = K + (size_t)M * D;
    float* Fc = V + (size_t)M * D;
    float* MLb = Fc + R;                 // R = M*H gate values
    const size_t need2 = ((size_t)3 * M * D + R + 2 * R * 2 + 2 * R * HD) * 4;
    const int splits = (ws_size >= need2) ? 2 : 1;
    float* Op = MLb + (size_t)splits * R * 2;

    const dim3 gblk(256);
    const dim3 ggrid((M / GBM) * (D / GBN));   // 512, %8==0 -> XCD swizzle ok
    gemm_bf16x3<<<ggrid, gblk, 0, stream>>>(x, Wq, Q, D, D);
    gemm_bf16x3<<<ggrid, gblk, 0, stream>>>(x, Wk, K, D, D);
    gemm_bf16x3<<<ggrid, gblk, 0, stream>>>(x, Wv, V, D, D);
    fgate_kernel<<<dim3(M), gblk, 0, stream>>>(x, Wf, bf, Fc);
    cumsum_kernel<<<dim3(B * H), gblk, 0, stream>>>(Fc);
    attn_kernel<<<dim3(S / QROWS, splits, B * H), gblk, 0, stream>>>(Q, K, V, Fc, Op, MLb, splits);
    attn_merge<<<dim3((int)(R / 4)), gblk, 0, stream>>>(Op, MLb, splits);
    gemm_bf16x3<<<ggrid, gblk, 0, stream>>>(Op, Wo, out, D, D);
}

// Round 7
// 977.830 us; speedup vs baseline: 4.1559x; 2.5306x over previous
//
#include <hip/hip_runtime.h>
#include <math.h>

#define B 2
#define S 2048
#define D 2048
#define H 32
#define HD 64
#define M (B*S)

typedef short s16x8 __attribute__((ext_vector_type(8)));
typedef float f32x4 __attribute__((ext_vector_type(4)));

// fp32 -> bf16 (RNE) and back, pure bit ops
__device__ __forceinline__ unsigned short f2bf(float f) {
    unsigned u = __float_as_uint(f);
    return (unsigned short)((u + 0x7fffu + ((u >> 16) & 1u)) >> 16);
}
__device__ __forceinline__ float bf2f(unsigned short h) {
    return __uint_as_float(((unsigned)h) << 16);
}

// ---------------------------------------------------------------------------
// bf16x3 MFMA GEMM: C[M,N] = A[M,K] * Bw[N,K]^T, fp32 in/out. (unchanged)
// ---------------------------------------------------------------------------
#define GBM 128
#define GBN 128
#define GBK 32
#define GLD (GBK + 8)

__global__ __launch_bounds__(256) void gemm_bf16x3(
    const float* __restrict__ A, const float* __restrict__ Bw,
    float* __restrict__ Cm, int Ndim, int Kdim)
{
    __shared__ unsigned short Ah[GBM * GLD], Al[GBM * GLD];
    __shared__ unsigned short Bh[GBN * GLD], Bl[GBN * GLD];
    const int tid = threadIdx.x;
    const int nwg = gridDim.x, cpx = nwg >> 3;
    const int wg = (blockIdx.x & 7) * cpx + (blockIdx.x >> 3);
    const int ntn = Ndim / GBN;
    const int m0 = (wg / ntn) * GBM, n0 = (wg % ntn) * GBN;

    const int row = tid >> 1;
    const int seg = (tid & 1) << 4;
    const float* Arow = A + (size_t)(m0 + row) * Kdim + seg;
    const float* Brow = Bw + (size_t)(n0 + row) * Kdim + seg;
    const int sbase = row * GLD + seg;

    const int wv = tid >> 6, lane = tid & 63;
    const int wr = (wv >> 1) << 6, wc = (wv & 1) << 6;
    const int fr = lane & 15, ko = (lane >> 4) << 3;

    f32x4 acc[4][4] = {};
    for (int k0 = 0; k0 < Kdim; k0 += GBK) {
        {
            float fa[16], fb[16];
            #pragma unroll
            for (int j4 = 0; j4 < 4; ++j4) {
                *(float4*)&fa[j4 * 4] = *(const float4*)(Arow + k0 + j4 * 4);
                *(float4*)&fb[j4 * 4] = *(const float4*)(Brow + k0 + j4 * 4);
            }
            unsigned short hv[16], lv[16], hw[16], lw[16];
            #pragma unroll
            for (int j = 0; j < 16; ++j) {
                unsigned short h = f2bf(fa[j]);
                hv[j] = h; lv[j] = f2bf(fa[j] - bf2f(h));
                unsigned short g = f2bf(fb[j]);
                hw[j] = g; lw[j] = f2bf(fb[j] - bf2f(g));
            }
            *(s16x8*)&Ah[sbase]     = *(s16x8*)&hv[0];
            *(s16x8*)&Ah[sbase + 8] = *(s16x8*)&hv[8];
            *(s16x8*)&Al[sbase]     = *(s16x8*)&lv[0];
            *(s16x8*)&Al[sbase + 8] = *(s16x8*)&lv[8];
            *(s16x8*)&Bh[sbase]     = *(s16x8*)&hw[0];
            *(s16x8*)&Bh[sbase + 8] = *(s16x8*)&hw[8];
            *(s16x8*)&Bl[sbase]     = *(s16x8*)&lw[0];
            *(s16x8*)&Bl[sbase + 8] = *(s16x8*)&lw[8];
        }
        __syncthreads();
        s16x8 fah[4], fal[4], fbh[4], fbl[4];
        #pragma unroll
        for (int m = 0; m < 4; ++m) {
            const int r = (wr + m * 16 + fr) * GLD + ko;
            fah[m] = *(s16x8*)&Ah[r];
            fal[m] = *(s16x8*)&Al[r];
        }
        #pragma unroll
        for (int n = 0; n < 4; ++n) {
            const int r = (wc + n * 16 + fr) * GLD + ko;
            fbh[n] = *(s16x8*)&Bh[r];
            fbl[n] = *(s16x8*)&Bl[r];
        }
        #pragma unroll
        for (int m = 0; m < 4; ++m)
            #pragma unroll
            for (int n = 0; n < 4; ++n) {
                acc[m][n] = __builtin_amdgcn_mfma_f32_16x16x32_bf16(fah[m], fbh[n], acc[m][n], 0, 0, 0);
                acc[m][n] = __builtin_amdgcn_mfma_f32_16x16x32_bf16(fah[m], fbl[n], acc[m][n], 0, 0, 0);
                acc[m][n] = __builtin_amdgcn_mfma_f32_16x16x32_bf16(fal[m], fbh[n], acc[m][n], 0, 0, 0);
            }
        __syncthreads();
    }
    const int crow0 = m0 + wr + ((lane >> 4) << 2);
    const int ccol0 = n0 + wc + fr;
    #pragma unroll
    for (int m = 0; m < 4; ++m)
        #pragma unroll
        for (int n = 0; n < 4; ++n)
            #pragma unroll
            for (int r = 0; r < 4; ++r)
                Cm[(size_t)(crow0 + m * 16 + r) * Ndim + ccol0 + n * 16] = acc[m][n][r];
}

// ---------------------------------------------------------------------------
// Forget gates + cumsum (unchanged)
// ---------------------------------------------------------------------------
__global__ __launch_bounds__(256) void fgate_kernel(
    const float* __restrict__ x, const float* __restrict__ Wf,
    const float* __restrict__ bfv, float* __restrict__ F)
{
    __shared__ float xs[D];
    const int bs = blockIdx.x;
    const float* xr = x + (size_t)bs * D;
    for (int i = threadIdx.x * 4; i < D; i += 256 * 4)
        *(float4*)&xs[i] = *(const float4*)&xr[i];
    __syncthreads();
    const int wave = threadIdx.x >> 6, lane = threadIdx.x & 63;
    for (int h = wave * 8; h < wave * 8 + 8; ++h) {
        const float* wr = Wf + (size_t)h * D;
        float sum = 0.f;
        for (int i = lane * 4; i < D; i += 64 * 4) {
            float4 w4 = *(const float4*)&wr[i];
            sum += xs[i]*w4.x + xs[i+1]*w4.y + xs[i+2]*w4.z + xs[i+3]*w4.w;
        }
        #pragma unroll
        for (int off = 32; off > 0; off >>= 1) sum += __shfl_down(sum, off);
        if (lane == 0) {
            float z = sum + bfv[h];
            F[(size_t)bs * H + h] = fminf(z, 0.f) - log1pf(expf(-fabsf(z)));
        }
    }
}

__global__ __launch_bounds__(256) void cumsum_kernel(float* __restrict__ F)
{
    const int b = blockIdx.x >> 5;
    const int h = blockIdx.x & 31;
    float* base = F + (size_t)b * S * H + h;
    __shared__ float part[256];
    const int t = threadIdx.x;
    float v[8];
    float run = 0.f;
    #pragma unroll
    for (int i = 0; i < 8; ++i) {
        v[i] = base[(size_t)(t * 8 + i) * H];
        run += v[i];
        v[i] = run;
    }
    part[t] = run;
    __syncthreads();
    for (int off = 1; off < 256; off <<= 1) {
        float add = (t >= off) ? part[t - off] : 0.f;
        __syncthreads();
        part[t] += add;
        __syncthreads();
    }
    const float offs = (t > 0) ? part[t - 1] : 0.f;
    #pragma unroll
    for (int i = 0; i < 8; ++i)
        base[(size_t)(t * 8 + i) * H] = v[i] + offs;
}

// ---------------------------------------------------------------------------
// MFMA flash attention with forget bias.
// Block = (b,h) x 128 q-rows; 4 waves, each owns 32 q-rows x full HD=64.
// Scores: mfma(Q,K^T) with Q split hi/lo bf16, K single bf16.
//   softmax(s_ij + c_i - c_j) == softmax(s_ij - c_j)  ->  c_i cancels.
// P -> bf16 via per-wave LDS tile; PV: mfma(P, Vt) with V staged transposed.
// Frag conventions (verified by gemm): A-frag row=lane&15, k=(lane>>4)*8;
// C row=(lane>>4)*4+r (+16m), col=lane&15 (+16n).
// ---------------------------------------------------------------------------
#define QBLK 128
#define KV 64
#define PLD 72          // bf16 row stride for attn LDS tiles
#define SCALE 0.125f    // 1/sqrt(64)

__global__ __launch_bounds__(256, 2) void attn_mfma(
    const float* __restrict__ Q, const float* __restrict__ Km,
    const float* __restrict__ V, const float* __restrict__ C,
    float* __restrict__ O)
{
    __shared__ unsigned short Qh[QBLK * PLD], Ql[QBLK * PLD];
    __shared__ unsigned short Ks[KV * PLD];
    __shared__ unsigned short Vt[HD * PLD];
    __shared__ unsigned short Pb[4 * 32 * PLD];
    __shared__ float cj[KV];

    const int qt = (int)gridDim.x - 1 - blockIdx.x;   // LPT: big tiles first
    const int b = blockIdx.z >> 5, h = blockIdx.z & 31;
    const int q0 = qt * QBLK;
    const int tid = threadIdx.x, wv = tid >> 6, lane = tid & 63;
    const int g = lane >> 4, fr = lane & 15;

    // ---- stage Q tile, split hi/lo ----
    {
        const int row = tid >> 1;            // 0..127
        const int seg = (tid & 1) << 5;      // 0 or 32
        const float* src = Q + (size_t)(b * S + q0 + row) * D + h * HD + seg;
        float f[32];
        #pragma unroll
        for (int j4 = 0; j4 < 8; ++j4)
            *(float4*)&f[j4 * 4] = *(const float4*)(src + j4 * 4);
        unsigned short hv[32], lv[32];
        #pragma unroll
        for (int e = 0; e < 32; ++e) {
            unsigned short hh = f2bf(f[e]);
            hv[e] = hh; lv[e] = f2bf(f[e] - bf2f(hh));
        }
        const int sb = row * PLD + seg;
        #pragma unroll
        for (int e = 0; e < 4; ++e) {
            *(s16x8*)&Qh[sb + e * 8] = *(s16x8*)&hv[e * 8];
            *(s16x8*)&Ql[sb + e * 8] = *(s16x8*)&lv[e * 8];
        }
    }
    __syncthreads();

    // ---- per-wave Q fragments in registers ----
    s16x8 qfh[2][2], qfl[2][2];   // [m][kd]
    #pragma unroll
    for (int m = 0; m < 2; ++m)
        #pragma unroll
        for (int kd = 0; kd < 2; ++kd) {
            const int r = (wv * 32 + m * 16 + fr) * PLD + kd * 32 + g * 8;
            qfh[m][kd] = *(s16x8*)&Qh[r];
            qfl[m][kd] = *(s16x8*)&Ql[r];
        }

    f32x4 Oa[2][4] = {};
    float mr[2][4], lr[2][4];
    #pragma unroll
    for (int m = 0; m < 2; ++m)
        #pragma unroll
        for (int r = 0; r < 4; ++r) { mr[m][r] = -INFINITY; lr[m][r] = 0.f; }

    const int imax = q0 + wv * 32 + 31;      // wave's last q row
    const int nj = (q0 + QBLK) / KV;
    unsigned short* Pw = &Pb[wv * 32 * PLD];

    for (int jt = 0; jt < nj; ++jt) {
        const int j0 = jt * KV;
        // ---- stage K (row-major) and V (transposed), bf16 ----
        {
            const int row = tid >> 2;            // 0..63 (j)
            const int seg = (tid & 3) << 4;      // 0,16,32,48 (d)
            const size_t goff = (size_t)(b * S + j0 + row) * D + h * HD + seg;
            float kf[16], vf[16];
            #pragma unroll
            for (int j4 = 0; j4 < 4; ++j4) {
                *(float4*)&kf[j4 * 4] = *(const float4*)(Km + goff + j4 * 4);
                *(float4*)&vf[j4 * 4] = *(const float4*)(V + goff + j4 * 4);
            }
            unsigned short kb[16];
            #pragma unroll
            for (int e = 0; e < 16; ++e) kb[e] = f2bf(kf[e]);
            *(s16x8*)&Ks[row * PLD + seg]     = *(s16x8*)&kb[0];
            *(s16x8*)&Ks[row * PLD + seg + 8] = *(s16x8*)&kb[8];
            #pragma unroll
            for (int e = 0; e < 16; ++e)
                Vt[(seg + e) * PLD + row] = f2bf(vf[e]);
            if (tid < KV)
                cj[tid] = C[(size_t)(b * S + j0 + tid) * H + h];
        }
        __syncthreads();

        if (j0 <= imax) {
            // ---- K fragments, QK^T MFMA (hi + lo) ----
            s16x8 kfr[4][2];
            #pragma unroll
            for (int n = 0; n < 4; ++n)
                #pragma unroll
                for (int kd = 0; kd < 2; ++kd)
                    kfr[n][kd] = *(s16x8*)&Ks[(n * 16 + fr) * PLD + kd * 32 + g * 8];
            f32x4 sa[2][4] = {};
            #pragma unroll
            for (int m = 0; m < 2; ++m)
                #pragma unroll
                for (int n = 0; n < 4; ++n) {
                    #pragma unroll
                    for (int kd = 0; kd < 2; ++kd) {
                        sa[m][n] = __builtin_amdgcn_mfma_f32_16x16x32_bf16(qfh[m][kd], kfr[n][kd], sa[m][n], 0, 0, 0);
                        sa[m][n] = __builtin_amdgcn_mfma_f32_16x16x32_bf16(qfl[m][kd], kfr[n][kd], sa[m][n], 0, 0, 0);
                    }
                }
            // ---- scores: scale, -c_j bias, causal mask ----
            float cjr[4];
            #pragma unroll
            for (int n = 0; n < 4; ++n) cjr[n] = cj[fr + 16 * n];
            float sc[2][4][4];
            float tm[2][4];
            #pragma unroll
            for (int m = 0; m < 2; ++m)
                #pragma unroll
                for (int r = 0; r < 4; ++r) tm[m][r] = -INFINITY;
            #pragma unroll
            for (int m = 0; m < 2; ++m)
                #pragma unroll
                for (int n = 0; n < 4; ++n)
                    #pragma unroll
                    for (int r = 0; r < 4; ++r) {
                        const int qrow = q0 + wv * 32 + m * 16 + g * 4 + r;
                        const int jcol = j0 + fr + 16 * n;
                        float s = sa[m][n][r] * SCALE - cjr[n];
                        s = (jcol <= qrow) ? s : -INFINITY;
                        sc[m][n][r] = s;
                        tm[m][r] = fmaxf(tm[m][r], s);
                    }
            // ---- row max across the 16-lane group ----
            #pragma unroll
            for (int m = 0; m < 2; ++m)
                #pragma unroll
                for (int r = 0; r < 4; ++r) {
                    float v = tm[m][r];
                    v = fmaxf(v, __shfl_xor(v, 1));
                    v = fmaxf(v, __shfl_xor(v, 2));
                    v = fmaxf(v, __shfl_xor(v, 4));
                    v = fmaxf(v, __shfl_xor(v, 8));
                    tm[m][r] = v;
                }
            // ---- online rescale ----
            #pragma unroll
            for (int m = 0; m < 2; ++m)
                #pragma unroll
                for (int r = 0; r < 4; ++r) {
                    const float newm = fmaxf(mr[m][r], tm[m][r]);
                    const float corr = __expf(mr[m][r] - newm);   // 0 when -inf
                    mr[m][r] = newm;
                    lr[m][r] *= corr;
                    #pragma unroll
                    for (int n = 0; n < 4; ++n) Oa[m][n][r] *= corr;
                }
            // ---- p = exp(s - m), row-sum, pack to LDS ----
            #pragma unroll
            for (int m = 0; m < 2; ++m) {
                float ps[4];
                #pragma unroll
                for (int r = 0; r < 4; ++r) ps[r] = 0.f;
                #pragma unroll
                for (int n = 0; n < 4; ++n)
                    #pragma unroll
                    for (int r = 0; r < 4; ++r) {
                        const float p = __expf(sc[m][n][r] - mr[m][r]);
                        ps[r] += p;
                        Pw[(m * 16 + g * 4 + r) * PLD + fr + 16 * n] = f2bf(p);
                    }
                #pragma unroll
                for (int r = 0; r < 4; ++r) {
                    float v = ps[r];
                    v += __shfl_xor(v, 1);
                    v += __shfl_xor(v, 2);
                    v += __shfl_xor(v, 4);
                    v += __shfl_xor(v, 8);
                    lr[m][r] += v;
                }
            }
            // ---- PV: P frags (own wave's LDS region) x Vt frags ----
            s16x8 pf[2][2], vfr[4][2];
            #pragma unroll
            for (int m = 0; m < 2; ++m)
                #pragma unroll
                for (int kj = 0; kj < 2; ++kj)
                    pf[m][kj] = *(s16x8*)&Pw[(fr + 16 * m) * PLD + kj * 32 + g * 8];
            #pragma unroll
            for (int n = 0; n < 4; ++n)
                #pragma unroll
                for (int kj = 0; kj < 2; ++kj)
                    vfr[n][kj] = *(s16x8*)&Vt[(n * 16 + fr) * PLD + kj * 32 + g * 8];
            #pragma unroll
            for (int m = 0; m < 2; ++m)
                #pragma unroll
                for (int n = 0; n < 4; ++n)
                    #pragma unroll
                    for (int kj = 0; kj < 2; ++kj)
                        Oa[m][n] = __builtin_amdgcn_mfma_f32_16x16x32_bf16(pf[m][kj], vfr[n][kj], Oa[m][n], 0, 0, 0);
        }
        __syncthreads();
    }

    // ---- normalize + store ----
    #pragma unroll
    for (int m = 0; m < 2; ++m)
        #pragma unroll
        for (int r = 0; r < 4; ++r) {
            const float inv = 1.f / lr[m][r];
            const size_t row = (size_t)(b * S + q0 + wv * 32 + m * 16 + g * 4 + r);
            #pragma unroll
            for (int n = 0; n < 4; ++n)
                O[row * D + h * HD + fr + 16 * n] = Oa[m][n][r] * inv;
        }
}

// ---------------------------------------------------------------------------
extern "C" void kernel_launch(void* const* d_in, const int* in_sizes, int n_in,
                              void* d_out, int out_size, void* d_ws, size_t ws_size,
                              hipStream_t stream) {
    const float* x  = (const float*)d_in[0];
    const float* Wq = (const float*)d_in[1];
    const float* Wk = (const float*)d_in[2];
    const float* Wv = (const float*)d_in[3];
    const float* Wf = (const float*)d_in[4];
    const float* bf = (const float*)d_in[5];
    const float* Wo = (const float*)d_in[6];
    float* out = (float*)d_out;

    // ws layout (floats): Q | K | V | Fc | O
    float* Q  = (float*)d_ws;
    float* K  = Q + (size_t)M * D;
    float* V  = K + (size_t)M * D;
    float* Fc = V + (size_t)M * D;
    float* O  = Fc + (size_t)M * H;

    const dim3 gblk(256);
    const dim3 ggrid((M / GBM) * (D / GBN));
    gemm_bf16x3<<<ggrid, gblk, 0, stream>>>(x, Wq, Q, D, D);
    gemm_bf16x3<<<ggrid, gblk, 0, stream>>>(x, Wk, K, D, D);
    gemm_bf16x3<<<ggrid, gblk, 0, stream>>>(x, Wv, V, D, D);
    fgate_kernel<<<dim3(M), gblk, 0, stream>>>(x, Wf, bf, Fc);
    cumsum_kernel<<<dim3(B * H), gblk, 0, stream>>>(Fc);
    attn_mfma<<<dim3(S / QBLK, 1, B * H), gblk, 0, stream>>>(Q, K, V, Fc, O);
    gemm_bf16x3<<<ggrid, gblk, 0, stream>>>(O, Wo, out, D, D);
}